// Round 10
// baseline (2632.992 us; speedup 1.0000x reference)
//
#include <hip/hip_runtime.h>

#define NN 50000
#define EE 400000
#define HH 512
#define LL 4
#define OUTC 250
#define MP 50048               // NN padded to multiple of 128
#define HH2 (HH*HH)
#define NPW 512                // pooling partial waves
#define NBLK 49                // ceil(NN/1024)
#define INV_SQRT_H 0.044194173824159216f
#define LBUF 16384             // u16 per LDS buffer: A 128x64 + B 128x64 (32 KiB)

typedef unsigned short u16;
typedef unsigned char u8;
typedef __attribute__((ext_vector_type(8))) unsigned short u16x8;
typedef __attribute__((ext_vector_type(8))) short s16x8;
typedef __attribute__((ext_vector_type(4))) float f32x4;
typedef __attribute__((ext_vector_type(2))) float f32x2;

__device__ __forceinline__ float b2f(u16 v) {
  union { unsigned u; float f; } c; c.u = ((unsigned)v) << 16; return c.f;
}
__device__ __forceinline__ u16 f2b(float f) {
  union { float f; unsigned u; } c; c.f = f;
  unsigned r = c.u + 0x7fffu + ((c.u >> 16) & 1u);
  return (u16)(r >> 16);
}
__device__ __forceinline__ float leakyf(float v) { return v > 0.f ? v : 0.2f * v; }

__device__ __forceinline__ void async16(const void* g, void* l) {
  __builtin_amdgcn_global_load_lds((const __attribute__((address_space(1))) void*)g,
                                   (__attribute__((address_space(3))) void*)l,
                                   16, 0, 0);
}

// ---------------- CSR build ----------------
__global__ void k_hist(const int* __restrict__ e0, const int* __restrict__ e1,
                       const int* __restrict__ e2, int* __restrict__ cnt) {
  int r = blockIdx.y;
  const int* dst = (r == 0 ? e0 : r == 1 ? e1 : e2) + EE;
  int i = blockIdx.x * 256 + threadIdx.x;
  if (i < EE) atomicAdd(&cnt[r * NN + dst[i]], 1);
}

__global__ void k_scan1(const int* __restrict__ cnt, int* __restrict__ offs,
                        float* __restrict__ invc, int* __restrict__ bsum) {
  int r = blockIdx.y, b = blockIdx.x, t = threadIdx.x;
  int i = b * 1024 + t;
  int v = (i < NN) ? cnt[r * NN + i] : 0;
  __shared__ int sm[1024];
  sm[t] = v;
  __syncthreads();
#pragma unroll
  for (int d = 1; d < 1024; d <<= 1) {
    int u = (t >= d) ? sm[t - d] : 0;
    __syncthreads();
    sm[t] += u;
    __syncthreads();
  }
  if (i < NN) {
    offs[r * (NN + 1) + i] = sm[t] - v;
    invc[r * NN + i] = 1.f / (float)(v > 1 ? v : 1);
  }
  if (t == 1023) bsum[r * NBLK + b] = sm[t];
}

__global__ void k_scan2(int* __restrict__ bsum) {
  int t = threadIdx.x;
  int r = t >> 6, lane = t & 63;
  if (r >= 3) return;
  int orig = (lane < NBLK) ? bsum[r * NBLK + lane] : 0;
  int v = orig;
#pragma unroll
  for (int d = 1; d < 64; d <<= 1) {
    int u = __shfl_up(v, d);
    if (lane >= d) v += u;
  }
  if (lane < NBLK) bsum[r * NBLK + lane] = v - orig;
}

__global__ void k_scan3(const int* __restrict__ bsum, int* __restrict__ offs,
                        int* __restrict__ cursor) {
  int r = blockIdx.y, b = blockIdx.x, t = threadIdx.x;
  int i = b * 1024 + t;
  if (i < NN) {
    int v = offs[r * (NN + 1) + i] + bsum[r * NBLK + b];
    offs[r * (NN + 1) + i] = v;
    cursor[r * NN + i] = v;
  }
  if (b == 0 && t == 0) offs[r * (NN + 1) + NN] = EE;
}

__global__ void k_fill(const int* __restrict__ e0, const int* __restrict__ e1,
                       const int* __restrict__ e2,
                       int* __restrict__ cursor, int* __restrict__ csr) {
  int r = blockIdx.y;
  const int* ep = (r == 0 ? e0 : r == 1 ? e1 : e2);
  int i = blockIdx.x * 256 + threadIdx.x;
  if (i >= EE) return;
  int s = ep[i], d = ep[EE + i];
  int slot = atomicAdd(&cursor[r * NN + d], 1);
  csr[r * EE + slot] = s;
}

// P[d] = sum_{k in row} pos[csr[k]] - deg * pos[d]   (atomic-free)
__global__ void k_pvec(const int* __restrict__ offs, const int* __restrict__ csr,
                       const float2* __restrict__ pos, float* __restrict__ P) {
  int r = blockIdx.y;
  int i = blockIdx.x * 256 + threadIdx.x;
  if (i >= NN) return;
  const int* o = offs + r * (NN + 1);
  const int* cs = csr + (size_t)r * EE;
  int b = o[i], e = o[i + 1];
  float sx = 0.f, sy = 0.f;
  for (int k = b; k < e; ++k) {
    float2 p = pos[cs[k]];
    sx += p.x; sy += p.y;
  }
  float2 pd = pos[i];
  float c = (float)(e - b);
  P[(size_t)r * NN * 2 + 2 * i]     = sx - c * pd.x;
  P[(size_t)r * NN * 2 + 2 * i + 1] = sy - c * pd.y;
}

// ---------------- weight prep: LDS-tiled transpose, all 14 512x512 mats in one launch ----------------
__global__ void k_transT14(const float* __restrict__ Wl, const float* __restrict__ W_pre,
                           const float* __restrict__ W_post,
                           u16* __restrict__ wlT, u16* __restrict__ wpreT,
                           u16* __restrict__ wpostT) {
  __shared__ float sm[32][33];
  int z = blockIdx.z;
  const float* Wm; u16* WTm;
  if (z < 12)      { Wm = Wl + (size_t)z * HH2;  WTm = wlT + (size_t)z * HH2; }
  else if (z == 12){ Wm = W_pre;                  WTm = wpreT; }
  else             { Wm = W_post;                 WTm = wpostT; }
  int r0 = blockIdx.y * 32, c0 = blockIdx.x * 32;
  int tx = threadIdx.x, ty = threadIdx.y;
#pragma unroll
  for (int i = 0; i < 4; ++i)
    sm[ty + i * 8][tx] = Wm[(size_t)(r0 + ty + i * 8) * HH + c0 + tx];
  __syncthreads();
#pragma unroll
  for (int i = 0; i < 4; ++i)
    WTm[(size_t)(c0 + ty + i * 8) * HH + r0 + tx] = f2b(sm[tx][ty + i * 8]);
}

__global__ void k_sum3T(const float* __restrict__ Wr, u16* __restrict__ WT) {
  __shared__ float sm[32][33];
  int l = blockIdx.z;
  const float* W3 = Wr + (size_t)l * 3 * HH2;
  u16* WTm = WT + (size_t)l * HH2;
  int r0 = blockIdx.y * 32, c0 = blockIdx.x * 32;
  int tx = threadIdx.x, ty = threadIdx.y;
#pragma unroll
  for (int i = 0; i < 4; ++i) {
    size_t idx = (size_t)(r0 + ty + i * 8) * HH + c0 + tx;
    sm[ty + i * 8][tx] = W3[idx] + W3[HH2 + idx] + W3[2 * (size_t)HH2 + idx];
  }
  __syncthreads();
#pragma unroll
  for (int i = 0; i < 4; ++i)
    WTm[(size_t)(c0 + ty + i * 8) * HH + r0 + tx] = f2b(sm[tx][ty + i * 8]);
}

__global__ void k_transpose_pad(const float* __restrict__ W, u16* __restrict__ WT,
                                int rows, int cols, int tcols) {
  int idx = blockIdx.x * 256 + threadIdx.x;
  if (idx >= rows * tcols) return;
  int r = idx % rows, c = idx / rows;
  float v = (c < cols) ? W[(size_t)r * cols + c] : 0.f;
  WT[(size_t)c * rows + r] = f2b(v);
}

// ---------------- misc: cvt x_window -> bf16 AND zero 5 pad regions, one launch ----------------
#define CVT_BLK ((NN * HH / 8 + 255) / 256)
__global__ void k_cvt_zero(const float* __restrict__ in, u16* __restrict__ out,
                           u16* a, u16* b, u16* c, u16* d, u16* e) {
  int blk = blockIdx.x;
  if (blk < CVT_BLK) {
    int i = blk * 256 + threadIdx.x;
    if (i >= NN * HH / 8) return;
    const float4 x = *(const float4*)(in + (size_t)i * 8);
    const float4 y = *(const float4*)(in + (size_t)i * 8 + 4);
    u16x8 o;
    o[0] = f2b(x.x); o[1] = f2b(x.y); o[2] = f2b(x.z); o[3] = f2b(x.w);
    o[4] = f2b(y.x); o[5] = f2b(y.y); o[6] = f2b(y.z); o[7] = f2b(y.w);
    *(u16x8*)(out + (size_t)i * 8) = o;
  } else {
    int i = (blk - CVT_BLK) * 256 + threadIdx.x;
    const int per = (MP - NN) * HH;
    if (i >= per * 5) return;
    int sel = i / per, rem = i - sel * per;
    u16* p = sel == 0 ? a : sel == 1 ? b : sel == 2 ? c : sel == 3 ? d : e;
    p[(size_t)NN * HH + rem] = 0;
  }
}

// ---------------- pooling ----------------
__global__ void k_kvec(const float* __restrict__ Wk, const float* __restrict__ seed,
                       float* __restrict__ kvec) {
  int l = blockIdx.x;
  const float* Wkl = Wk + (size_t)l * HH2;
  const float* sdl = seed + (size_t)l * HH;
  float* kv = kvec + (size_t)l * HH;
  int w = threadIdx.x >> 6, lane = threadIdx.x & 63;
  float sv[8];
#pragma unroll
  for (int i = 0; i < 8; ++i) sv[i] = sdl[lane * 8 + i];
  for (int row = w; row < HH; row += 8) {
    const float* p = Wkl + (size_t)row * HH + lane * 8;
    float d = 0.f;
#pragma unroll
    for (int i = 0; i < 8; ++i) d += p[i] * sv[i];
#pragma unroll
    for (int o = 32; o > 0; o >>= 1) d += __shfl_xor(d, o);
    if (lane == 0) kv[row] = d;
  }
}

__global__ void k_pool2g(const float* __restrict__ part, const float* __restrict__ Wv,
                         const float* __restrict__ Wg, float* __restrict__ gterm) {
  __shared__ float red[512];
  __shared__ float gv[HH];
  __shared__ float g[HH];
  int t = threadIdx.x;
  red[t] = part[(size_t)t * 514];
  __syncthreads();
  for (int s = 256; s > 0; s >>= 1) {
    if (t < s) red[t] = fmaxf(red[t], red[t + s]);
    __syncthreads();
  }
  float M = red[0];
  float s = 0.f, z = 0.f;
  for (int w = 0; w < NPW; ++w) {
    const float* p = part + (size_t)w * 514;
    float e = __expf(p[0] - M);
    z += e * p[1];
    s += e * p[2 + t];
  }
  gv[t] = s / z;
  __syncthreads();
  float a = 0.f;
  for (int i = 0; i < HH; ++i) a += gv[i] * Wv[(size_t)i * HH + t];
  g[t] = a;
  __syncthreads();
  float b = 0.f;
  for (int i = 0; i < HH; ++i) b += g[i] * Wg[(size_t)i * HH + t];
  gterm[t] = b;
}

// ---------------- fused SpMM fp8-gather (y<3) + pool pass 1 on x8 (y==3) ----------------
__device__ __forceinline__ void acc_fp8x8(float* acc, uint2 v) {
  f32x2 a0 = __builtin_amdgcn_cvt_pk_f32_fp8(v.x, false);
  f32x2 a1 = __builtin_amdgcn_cvt_pk_f32_fp8(v.x, true);
  f32x2 a2 = __builtin_amdgcn_cvt_pk_f32_fp8(v.y, false);
  f32x2 a3 = __builtin_amdgcn_cvt_pk_f32_fp8(v.y, true);
  acc[0] += a0[0]; acc[1] += a0[1]; acc[2] += a1[0]; acc[3] += a1[1];
  acc[4] += a2[0]; acc[5] += a2[1]; acc[6] += a3[0]; acc[7] += a3[1];
}

__device__ __forceinline__ void unpack_fp8x8(float* xl, uint2 v) {
  f32x2 a0 = __builtin_amdgcn_cvt_pk_f32_fp8(v.x, false);
  f32x2 a1 = __builtin_amdgcn_cvt_pk_f32_fp8(v.x, true);
  f32x2 a2 = __builtin_amdgcn_cvt_pk_f32_fp8(v.y, false);
  f32x2 a3 = __builtin_amdgcn_cvt_pk_f32_fp8(v.y, true);
  xl[0] = a0[0]; xl[1] = a0[1]; xl[2] = a1[0]; xl[3] = a1[1];
  xl[4] = a2[0]; xl[5] = a2[1]; xl[6] = a3[0]; xl[7] = a3[1];
}

__global__ void k_spmm_pool(const int* __restrict__ offs, const int* __restrict__ csr,
                            const float* __restrict__ invc, const float* __restrict__ P,
                            const float* __restrict__ wposL,
                            const u8* __restrict__ x8,
                            u16* __restrict__ agg, const float* __restrict__ kvec,
                            float* __restrict__ part) {
  int r = blockIdx.y;
  int lane = threadIdx.x & 63;
  if (r == 3) {
    // ---- pool1: per-wave online softmax-weighted sum over x8 (fp8, 25.6 MB) ----
    if (blockIdx.x >= NPW / 4) return;
    int gw = (blockIdx.x * 256 + threadIdx.x) >> 6;
    float kl[8];
#pragma unroll
    for (int i = 0; i < 8; ++i) kl[i] = kvec[lane * 8 + i];
    float m = -1e30f, Z = 0.f;
    float acc[8] = {0, 0, 0, 0, 0, 0, 0, 0};
    for (int n = gw; n < NN; n += NPW) {
      uint2 v = *(const uint2*)(x8 + (size_t)n * HH + lane * 8);
      float xl[8], d = 0.f;
      unpack_fp8x8(xl, v);
#pragma unroll
      for (int i = 0; i < 8; ++i) d += xl[i] * kl[i];
#pragma unroll
      for (int o = 32; o > 0; o >>= 1) d += __shfl_xor(d, o);
      d *= INV_SQRT_H;
      float mn = fmaxf(m, d);
      float c = __expf(m - mn), w = __expf(d - mn);
      Z = Z * c + w;
#pragma unroll
      for (int i = 0; i < 8; ++i) acc[i] = acc[i] * c + w * xl[i];
      m = mn;
    }
    float* p = part + (size_t)gw * 514;
#pragma unroll
    for (int i = 0; i < 8; ++i) p[2 + lane * 8 + i] = acc[i];
    if (lane == 0) { p[0] = m; p[1] = Z; }
    return;
  }
  // ---- spmm: agg_r = (A_r @ x8 + P_r @ Wpos_r) * invc_r ----
  int wv = __builtin_amdgcn_readfirstlane((int)(blockIdx.x * 256 + threadIdx.x) >> 6);
  if (wv >= NN) return;
  const int* o = offs + r * (NN + 1);
  const int* cs = csr + (size_t)r * EE;
  const float* wpos = wposL + (size_t)r * 2 * HH;
  int beg = o[wv], end = o[wv + 1];
  float acc[8] = {0, 0, 0, 0, 0, 0, 0, 0};
  int k = beg;
  for (; k + 7 < end; k += 8) {        // 8 gathers in flight (8B/lane fp8)
    int s[8];
#pragma unroll
    for (int j = 0; j < 8; ++j) s[j] = cs[k + j];
    uint2 v[8];
#pragma unroll
    for (int j = 0; j < 8; ++j) v[j] = *(const uint2*)(x8 + (size_t)s[j] * HH + lane * 8);
#pragma unroll
    for (int j = 0; j < 8; ++j) acc_fp8x8(acc, v[j]);
  }
  for (; k + 3 < end; k += 4) {
    int s[4];
#pragma unroll
    for (int j = 0; j < 4; ++j) s[j] = cs[k + j];
    uint2 v[4];
#pragma unroll
    for (int j = 0; j < 4; ++j) v[j] = *(const uint2*)(x8 + (size_t)s[j] * HH + lane * 8);
#pragma unroll
    for (int j = 0; j < 4; ++j) acc_fp8x8(acc, v[j]);
  }
  for (; k < end; ++k) {
    uint2 v0 = *(const uint2*)(x8 + (size_t)cs[k] * HH + lane * 8);
    acc_fp8x8(acc, v0);
  }
  float px = P[(size_t)r * NN * 2 + 2 * wv], py = P[(size_t)r * NN * 2 + 2 * wv + 1];
  float ic = invc[(size_t)r * NN + wv];
  u16x8 out;
#pragma unroll
  for (int i = 0; i < 8; ++i) {
    float w0 = wpos[lane * 8 + i];
    float w1 = wpos[HH + lane * 8 + i];
    float v = (acc[i] + px * w0 + py * w1) * ic;
    out[i] = f2b(v);
  }
  // nt: agg streams 153 MB during the gather — keep it out of L3 so x8 stays resident
  __builtin_nontemporal_store(out, (u16x8*)(agg + ((size_t)r * MP + wv) * HH + lane * 8));
}

// ---------------- GEMM: 128x128 tile, 4 waves, single-barrier 2-phase dbuf (T3 minimal) ----------------
// Per K-step: STAGE(next, buf^1) -> compute(buf[cur]) -> __syncthreads() [vmcnt(0)+barrier].
// Loads fly during the MFMA phase; WAR-safe: buf^1's readers finished before prev barrier.
// mode 0: outB = bf16(leaky(C*alpha + gvec[col])); if out8, fp8 copy staged via LDS.
// mode 1: outF = C + bias (bounds-checked)
__global__ __launch_bounds__(256) void k_gemm(
    const u16* __restrict__ A0, const u16* __restrict__ A1,
    const u16* __restrict__ A2, const u16* __restrict__ A3,
    const u16* __restrict__ B0, const u16* __restrict__ B1,
    const u16* __restrict__ B2, const u16* __restrict__ B3,
    int nkt, int mode, float alpha, const float* __restrict__ gvec,
    u16* __restrict__ outB, u8* __restrict__ out8, float* __restrict__ outF,
    const float* __restrict__ bias, int M, int Nout, int G, int gx)
{
  __shared__ u16 lds[2 * LBUF];   // 64 KiB: 2 x (A 128x64 + B 128x64)
  const int tid = threadIdx.x;
  const int wave = tid >> 6, lane = tid & 63;
  const int wm = (wave >> 1) * 64, wn = (wave & 1) * 64;

  // bijective XCD swizzle (m204), col-fastest tile order
  const int gid = blockIdx.x;
  const int q = G >> 3, rr = G & 7;
  const int xk = gid & 7, idx = gid >> 3;
  const int tl = xk * q + (xk < rr ? xk : rr) + idx;
  const int rowM0 = (tl / gx) * 128, colN0 = (tl % gx) * 128;

  f32x4 acc[4][4];
#pragma unroll
  for (int i = 0; i < 4; ++i)
#pragma unroll
    for (int j = 0; j < 4; ++j) acc[i][j] = (f32x4){0.f, 0.f, 0.f, 0.f};

  const int rowT = wave * 8 + (lane >> 3);
  const int c8 = lane & 7;

  auto STAGE = [&](int buf, int kt) {
    const int kb = kt >> 3;
    const int koff = (kt & 7) * 64;
    const u16* As = kb == 0 ? A0 : (kb == 1 ? A1 : (kb == 2 ? A2 : A3));
    const u16* Bs = kb == 0 ? B0 : (kb == 1 ? B1 : (kb == 2 ? B2 : B3));
    u16* la = lds + buf * LBUF;
    u16* lb = la + 8192;
#pragma unroll
    for (int i = 0; i < 4; ++i) {
      const int r = i * 32 + rowT;
      const int scol = (c8 ^ (r & 7)) * 8;      // inverse-swizzled source (rule #21)
      async16(As + (size_t)(rowM0 + r) * HH + koff + scol, la + i * 2048 + wave * 512);
      async16(Bs + (size_t)(colN0 + r) * HH + koff + scol, lb + i * 2048 + wave * 512);
    }
  };

  // hoisted kt-invariant LDS read offsets (u16 units)
  int aoff[2][4], boff[2][4];
#pragma unroll
  for (int K0 = 0; K0 < 2; ++K0)
#pragma unroll
    for (int f = 0; f < 4; ++f) {
      const int cb = K0 * 4 + (lane >> 4);
      const int mm = wm + f * 16 + (lane & 15);
      const int nn = wn + f * 16 + (lane & 15);
      aoff[K0][f] = mm * 64 + ((cb ^ (mm & 7)) << 3);
      boff[K0][f] = nn * 64 + ((cb ^ (nn & 7)) << 3);
    }

  STAGE(0, 0);
  __syncthreads();                 // buf0 staged
  for (int kt = 0; kt < nkt; ++kt) {
    const int cur = kt & 1;
    if (kt + 1 < nkt) STAGE(cur ^ 1, kt + 1);   // issue next-tile loads (fly during MFMA)
    const u16* la = lds + cur * LBUF;
    const u16* lb = la + 8192;
#pragma unroll
    for (int K0 = 0; K0 < 2; ++K0) {
      s16x8 af[4], bfr[4];
#pragma unroll
      for (int f = 0; f < 4; ++f) {
        af[f] = *(const s16x8*)&la[aoff[K0][f]];
        bfr[f] = *(const s16x8*)&lb[boff[K0][f]];
      }
#pragma unroll
      for (int fm = 0; fm < 4; ++fm)
#pragma unroll
        for (int fn = 0; fn < 4; ++fn)
          acc[fm][fn] = __builtin_amdgcn_mfma_f32_16x16x32_bf16(af[fm], bfr[fn], acc[fm][fn], 0, 0, 0);
    }
    __syncthreads();               // vmcnt(0)+barrier: next buf ready, this buf free
  }

  u8* l8 = (u8*)lds;   // safe to reuse after the final barrier
#pragma unroll
  for (int fm = 0; fm < 4; ++fm) {
#pragma unroll
    for (int fn = 0; fn < 4; ++fn) {
#pragma unroll
      for (int r = 0; r < 4; ++r) {
        const int rit = wm + fm * 16 + ((lane >> 4) << 2) + r;   // row in tile (m89 layout)
        const int cit = wn + fn * 16 + (lane & 15);              // col in tile
        const int row = rowM0 + rit, col = colN0 + cit;
        float v = acc[fm][fn][r];
        if (mode == 0) {
          v = leakyf(v * alpha + (gvec ? gvec[col] : 0.f));
          outB[(size_t)row * HH + col] = f2b(v);
          if (out8) {
            int pk = __builtin_amdgcn_cvt_pk_fp8_f32(v, v, 0, false);
            l8[rit * 128 + cit] = (u8)pk;
          }
        } else {
          if (row < M && col < Nout)
            outF[(size_t)row * Nout + col] = v + (bias ? bias[col] : 0.f);
        }
      }
    }
  }
  if (mode == 0 && out8) {
    __syncthreads();
    const int rit = tid >> 1, hoff = (tid & 1) * 64;
    const uint4* src = (const uint4*)(l8 + rit * 128 + hoff);
    uint4 v0 = src[0], v1 = src[1], v2 = src[2], v3 = src[3];
    uint4* dst = (uint4*)(out8 + (size_t)(rowM0 + rit) * HH + colN0 + hoff);
    dst[0] = v0; dst[1] = v1; dst[2] = v2; dst[3] = v3;
  }
}

// ---------------- host ----------------
extern "C" void kernel_launch(void* const* d_in, const int* in_sizes, int n_in,
                              void* d_out, int out_size, void* d_ws, size_t ws_size,
                              hipStream_t stream) {
  (void)in_sizes; (void)n_in; (void)out_size;
  const float* x_window = (const float*)d_in[0];
  const float* x_pos    = (const float*)d_in[1];
  const int*   e0 = (const int*)d_in[2];
  const int*   e1 = (const int*)d_in[3];
  const int*   e2 = (const int*)d_in[4];
  const float* W_pre  = (const float*)d_in[5];
  const float* W_post = (const float*)d_in[6];
  const float* Wl   = (const float*)d_in[7];
  const float* Wr   = (const float*)d_in[8];
  const float* Wpos = (const float*)d_in[9];
  const float* Wg   = (const float*)d_in[10];
  const float* seed = (const float*)d_in[11];
  const float* Wk   = (const float*)d_in[12];
  const float* Wv   = (const float*)d_in[13];
  const float* W_out= (const float*)d_in[14];
  const float* b_out= (const float*)d_in[15];
  float* out = (float*)d_out;

  char* base = (char*)d_ws;
  size_t off = 0;
  auto alloc = [&](size_t bytes) -> char* {
    char* p = base + off;
    off += (bytes + 255) & ~(size_t)255;
    return p;
  };
  u16* x_a   = (u16*)alloc((size_t)MP * HH * 2);
  u16* x_b   = (u16*)alloc((size_t)MP * HH * 2);
  u16* agg0  = (u16*)alloc((size_t)MP * HH * 2);
  u16* agg1  = (u16*)alloc((size_t)MP * HH * 2);
  u16* agg2  = (u16*)alloc((size_t)MP * HH * 2);
  u8*  x8    = (u8*)alloc((size_t)MP * HH);
  u16* wlT   = (u16*)alloc((size_t)12 * HH2 * 2);
  u16* wrsT  = (u16*)alloc((size_t)4 * HH2 * 2);
  u16* wpreT = (u16*)alloc((size_t)HH2 * 2);
  u16* wpostT= (u16*)alloc((size_t)HH2 * 2);
  u16* woutT = (u16*)alloc((size_t)256 * HH * 2);
  int* offs  = (int*)alloc((size_t)3 * (NN + 1) * 4);
  int* curs  = (int*)alloc((size_t)3 * NN * 4);    // dead after CSR build -> part overlay
  int* cnt   = (int*)alloc((size_t)3 * NN * 4);    // dead after scan
  int* csr   = (int*)alloc((size_t)3 * EE * 4);
  float* invc = (float*)alloc((size_t)3 * NN * 4);
  float* P    = (float*)alloc((size_t)3 * NN * 2 * 4);
  float* kvec  = (float*)alloc((size_t)LL * HH * 4);
  float* gterm = (float*)alloc(HH * 4);
  int* bsum  = (int*)alloc((size_t)3 * NBLK * 4);
  float* part  = (float*)curs;   // NPW*514*4 = 1.05 MB fits in curs+cnt (1.2 MB)
  if (off > ws_size) return;

  hipMemsetAsync(cnt, 0, (size_t)3 * NN * 4, stream);

  k_hist<<<dim3((EE + 255) / 256, 3), 256, 0, stream>>>(e0, e1, e2, cnt);
  k_scan1<<<dim3(NBLK, 3), 1024, 0, stream>>>(cnt, offs, invc, bsum);
  k_scan2<<<1, 256, 0, stream>>>(bsum);
  k_scan3<<<dim3(NBLK, 3), 1024, 0, stream>>>(bsum, offs, curs);
  k_fill<<<dim3((EE + 255) / 256, 3), 256, 0, stream>>>(e0, e1, e2, curs, csr);
  k_pvec<<<dim3((NN + 255) / 256, 3), 256, 0, stream>>>(offs, csr, (const float2*)x_pos, P);

  k_transT14<<<dim3(16, 16, 14), dim3(32, 8), 0, stream>>>(Wl, W_pre, W_post,
                                                           wlT, wpreT, wpostT);
  k_sum3T<<<dim3(16, 16, 4), dim3(32, 8), 0, stream>>>(Wr, wrsT);
  k_transpose_pad<<<(HH * 256) / 256, 256, 0, stream>>>(W_out, woutT, HH, OUTC, 256);
  k_kvec<<<LL, 512, 0, stream>>>(Wk, seed, kvec);

  const int padBlk = ((MP - NN) * HH * 5 + 255) / 256;
  k_cvt_zero<<<CVT_BLK + padBlk, 256, 0, stream>>>(x_window, x_b, x_a, x_b, agg0, agg1, agg2);

  const u16* nul = nullptr;
  const int G4 = 4 * (MP / 128), G2 = 2 * (MP / 128);
  // pretransform: t = leaky(xw @ W_pre) -> agg0 ; x0 = leaky(t @ W_post) -> x_a (+fp8)
  k_gemm<<<G4, 256, 0, stream>>>(x_b, nul, nul, nul, wpreT, nul, nul, nul,
                                 8, 0, 1.f, nullptr, agg0, nullptr, nullptr, nullptr, NN, HH, G4, 4);
  k_gemm<<<G4, 256, 0, stream>>>(agg0, nul, nul, nul, wpostT, nul, nul, nul,
                                 8, 0, 1.f, nullptr, x_a, x8, nullptr, nullptr, NN, HH, G4, 4);

  u16* cur = x_a; u16* nxt = x_b;
  for (int l = 0; l < LL; ++l) {
    k_spmm_pool<<<dim3(NN / 4, 4), 256, 0, stream>>>(offs, csr, invc, P,
                                                     Wpos + (size_t)l * 3 * 2 * HH, x8, agg0,
                                                     kvec + (size_t)l * HH, part);
    k_pool2g<<<1, 512, 0, stream>>>(part, Wv + (size_t)l * HH2, Wg + (size_t)l * HH2, gterm);
    k_gemm<<<G4, 256, 0, stream>>>(
        agg0, agg1, agg2, cur,
        wlT + (size_t)(l * 3 + 0) * HH2, wlT + (size_t)(l * 3 + 1) * HH2,
        wlT + (size_t)(l * 3 + 2) * HH2, wrsT + (size_t)l * HH2,
        32, 0, (1.f / 3.f), gterm, nxt, (l < LL - 1) ? x8 : nullptr, nullptr, nullptr, NN, HH, G4, 4);
    u16* t = cur; cur = nxt; nxt = t;
  }
  // final projection: out = x @ W_out + b_out
  k_gemm<<<G2, 256, 0, stream>>>(cur, nul, nul, nul, woutT, nul, nul, nul,
                                 8, 1, 1.f, nullptr, nullptr, nullptr, out, b_out, NN, OUTC, G2, 2);
}

// Round 11
// 1934.616 us; speedup vs baseline: 1.3610x; 1.3610x over previous
//
#include <hip/hip_runtime.h>

#define NN 50000
#define EE 400000
#define HH 512
#define LL 4
#define OUTC 250
#define MP 50048               // NN padded to multiple of 128
#define HH2 (HH*HH)
#define NPW 512                // pooling partial waves
#define NBLK 49                // ceil(NN/1024)
#define INV_SQRT_H 0.044194173824159216f

typedef unsigned short u16;
typedef unsigned char u8;
typedef __attribute__((ext_vector_type(8))) unsigned short u16x8;
typedef __attribute__((ext_vector_type(8))) short s16x8;
typedef __attribute__((ext_vector_type(4))) float f32x4;
typedef __attribute__((ext_vector_type(2))) float f32x2;

__device__ __forceinline__ float b2f(u16 v) {
  union { unsigned u; float f; } c; c.u = ((unsigned)v) << 16; return c.f;
}
__device__ __forceinline__ u16 f2b(float f) {
  union { float f; unsigned u; } c; c.f = f;
  unsigned r = c.u + 0x7fffu + ((c.u >> 16) & 1u);
  return (u16)(r >> 16);
}
__device__ __forceinline__ float leakyf(float v) { return v > 0.f ? v : 0.2f * v; }

__device__ __forceinline__ void async16(const void* g, void* l) {
  __builtin_amdgcn_global_load_lds((const __attribute__((address_space(1))) void*)g,
                                   (__attribute__((address_space(3))) void*)l,
                                   16, 0, 0);
}

// ---------------- CSR build ----------------
__global__ void k_hist(const int* __restrict__ e0, const int* __restrict__ e1,
                       const int* __restrict__ e2, int* __restrict__ cnt) {
  int r = blockIdx.y;
  const int* dst = (r == 0 ? e0 : r == 1 ? e1 : e2) + EE;
  int i = blockIdx.x * 256 + threadIdx.x;
  if (i < EE) atomicAdd(&cnt[r * NN + dst[i]], 1);
}

__global__ void k_scan1(const int* __restrict__ cnt, int* __restrict__ offs,
                        float* __restrict__ invc, int* __restrict__ bsum) {
  int r = blockIdx.y, b = blockIdx.x, t = threadIdx.x;
  int i = b * 1024 + t;
  int v = (i < NN) ? cnt[r * NN + i] : 0;
  __shared__ int sm[1024];
  sm[t] = v;
  __syncthreads();
#pragma unroll
  for (int d = 1; d < 1024; d <<= 1) {
    int u = (t >= d) ? sm[t - d] : 0;
    __syncthreads();
    sm[t] += u;
    __syncthreads();
  }
  if (i < NN) {
    offs[r * (NN + 1) + i] = sm[t] - v;
    invc[r * NN + i] = 1.f / (float)(v > 1 ? v : 1);
  }
  if (t == 1023) bsum[r * NBLK + b] = sm[t];
}

__global__ void k_scan2(int* __restrict__ bsum) {
  int t = threadIdx.x;
  int r = t >> 6, lane = t & 63;
  if (r >= 3) return;
  int orig = (lane < NBLK) ? bsum[r * NBLK + lane] : 0;
  int v = orig;
#pragma unroll
  for (int d = 1; d < 64; d <<= 1) {
    int u = __shfl_up(v, d);
    if (lane >= d) v += u;
  }
  if (lane < NBLK) bsum[r * NBLK + lane] = v - orig;
}

__global__ void k_scan3(const int* __restrict__ bsum, int* __restrict__ offs,
                        int* __restrict__ cursor) {
  int r = blockIdx.y, b = blockIdx.x, t = threadIdx.x;
  int i = b * 1024 + t;
  if (i < NN) {
    int v = offs[r * (NN + 1) + i] + bsum[r * NBLK + b];
    offs[r * (NN + 1) + i] = v;
    cursor[r * NN + i] = v;
  }
  if (b == 0 && t == 0) offs[r * (NN + 1) + NN] = EE;
}

__global__ void k_fill(const int* __restrict__ e0, const int* __restrict__ e1,
                       const int* __restrict__ e2,
                       int* __restrict__ cursor, int* __restrict__ csr) {
  int r = blockIdx.y;
  const int* ep = (r == 0 ? e0 : r == 1 ? e1 : e2);
  int i = blockIdx.x * 256 + threadIdx.x;
  if (i >= EE) return;
  int s = ep[i], d = ep[EE + i];
  int slot = atomicAdd(&cursor[r * NN + d], 1);
  csr[r * EE + slot] = s;
}

// P[d] = sum_{k in row} pos[csr[k]] - deg * pos[d]   (atomic-free)
__global__ void k_pvec(const int* __restrict__ offs, const int* __restrict__ csr,
                       const float2* __restrict__ pos, float* __restrict__ P) {
  int r = blockIdx.y;
  int i = blockIdx.x * 256 + threadIdx.x;
  if (i >= NN) return;
  const int* o = offs + r * (NN + 1);
  const int* cs = csr + (size_t)r * EE;
  int b = o[i], e = o[i + 1];
  float sx = 0.f, sy = 0.f;
  for (int k = b; k < e; ++k) {
    float2 p = pos[cs[k]];
    sx += p.x; sy += p.y;
  }
  float2 pd = pos[i];
  float c = (float)(e - b);
  P[(size_t)r * NN * 2 + 2 * i]     = sx - c * pd.x;
  P[(size_t)r * NN * 2 + 2 * i + 1] = sy - c * pd.y;
}

// ---------------- weight prep: LDS-tiled transpose, all 14 512x512 mats in one launch ----------------
__global__ void k_transT14(const float* __restrict__ Wl, const float* __restrict__ W_pre,
                           const float* __restrict__ W_post,
                           u16* __restrict__ wlT, u16* __restrict__ wpreT,
                           u16* __restrict__ wpostT) {
  __shared__ float sm[32][33];
  int z = blockIdx.z;
  const float* Wm; u16* WTm;
  if (z < 12)      { Wm = Wl + (size_t)z * HH2;  WTm = wlT + (size_t)z * HH2; }
  else if (z == 12){ Wm = W_pre;                  WTm = wpreT; }
  else             { Wm = W_post;                 WTm = wpostT; }
  int r0 = blockIdx.y * 32, c0 = blockIdx.x * 32;
  int tx = threadIdx.x, ty = threadIdx.y;
#pragma unroll
  for (int i = 0; i < 4; ++i)
    sm[ty + i * 8][tx] = Wm[(size_t)(r0 + ty + i * 8) * HH + c0 + tx];
  __syncthreads();
#pragma unroll
  for (int i = 0; i < 4; ++i)
    WTm[(size_t)(c0 + ty + i * 8) * HH + r0 + tx] = f2b(sm[tx][ty + i * 8]);
}

__global__ void k_sum3T(const float* __restrict__ Wr, u16* __restrict__ WT) {
  __shared__ float sm[32][33];
  int l = blockIdx.z;
  const float* W3 = Wr + (size_t)l * 3 * HH2;
  u16* WTm = WT + (size_t)l * HH2;
  int r0 = blockIdx.y * 32, c0 = blockIdx.x * 32;
  int tx = threadIdx.x, ty = threadIdx.y;
#pragma unroll
  for (int i = 0; i < 4; ++i) {
    size_t idx = (size_t)(r0 + ty + i * 8) * HH + c0 + tx;
    sm[ty + i * 8][tx] = W3[idx] + W3[HH2 + idx] + W3[2 * (size_t)HH2 + idx];
  }
  __syncthreads();
#pragma unroll
  for (int i = 0; i < 4; ++i)
    WTm[(size_t)(c0 + ty + i * 8) * HH + r0 + tx] = f2b(sm[tx][ty + i * 8]);
}

__global__ void k_transpose_pad(const float* __restrict__ W, u16* __restrict__ WT,
                                int rows, int cols, int tcols) {
  int idx = blockIdx.x * 256 + threadIdx.x;
  if (idx >= rows * tcols) return;
  int r = idx % rows, c = idx / rows;
  float v = (c < cols) ? W[(size_t)r * cols + c] : 0.f;
  WT[(size_t)c * rows + r] = f2b(v);
}

// ---------------- misc: cvt x_window -> bf16 AND zero 5 pad regions, one launch ----------------
#define CVT_BLK ((NN * HH / 8 + 255) / 256)
__global__ void k_cvt_zero(const float* __restrict__ in, u16* __restrict__ out,
                           u16* a, u16* b, u16* c, u16* d, u16* e) {
  int blk = blockIdx.x;
  if (blk < CVT_BLK) {
    int i = blk * 256 + threadIdx.x;
    if (i >= NN * HH / 8) return;
    const float4 x = *(const float4*)(in + (size_t)i * 8);
    const float4 y = *(const float4*)(in + (size_t)i * 8 + 4);
    u16x8 o;
    o[0] = f2b(x.x); o[1] = f2b(x.y); o[2] = f2b(x.z); o[3] = f2b(x.w);
    o[4] = f2b(y.x); o[5] = f2b(y.y); o[6] = f2b(y.z); o[7] = f2b(y.w);
    *(u16x8*)(out + (size_t)i * 8) = o;
  } else {
    int i = (blk - CVT_BLK) * 256 + threadIdx.x;
    const int per = (MP - NN) * HH;
    if (i >= per * 5) return;
    int sel = i / per, rem = i - sel * per;
    u16* p = sel == 0 ? a : sel == 1 ? b : sel == 2 ? c : sel == 3 ? d : e;
    p[(size_t)NN * HH + rem] = 0;
  }
}

// ---------------- pooling ----------------
__global__ void k_kvec(const float* __restrict__ Wk, const float* __restrict__ seed,
                       float* __restrict__ kvec) {
  int l = blockIdx.x;
  const float* Wkl = Wk + (size_t)l * HH2;
  const float* sdl = seed + (size_t)l * HH;
  float* kv = kvec + (size_t)l * HH;
  int w = threadIdx.x >> 6, lane = threadIdx.x & 63;
  float sv[8];
#pragma unroll
  for (int i = 0; i < 8; ++i) sv[i] = sdl[lane * 8 + i];
  for (int row = w; row < HH; row += 8) {
    const float* p = Wkl + (size_t)row * HH + lane * 8;
    float d = 0.f;
#pragma unroll
    for (int i = 0; i < 8; ++i) d += p[i] * sv[i];
#pragma unroll
    for (int o = 32; o > 0; o >>= 1) d += __shfl_xor(d, o);
    if (lane == 0) kv[row] = d;
  }
}

__global__ void k_pool2g(const float* __restrict__ part, const float* __restrict__ Wv,
                         const float* __restrict__ Wg, float* __restrict__ gterm) {
  __shared__ float red[512];
  __shared__ float gv[HH];
  __shared__ float g[HH];
  int t = threadIdx.x;
  red[t] = part[(size_t)t * 514];
  __syncthreads();
  for (int s = 256; s > 0; s >>= 1) {
    if (t < s) red[t] = fmaxf(red[t], red[t + s]);
    __syncthreads();
  }
  float M = red[0];
  float s = 0.f, z = 0.f;
  for (int w = 0; w < NPW; ++w) {
    const float* p = part + (size_t)w * 514;
    float e = __expf(p[0] - M);
    z += e * p[1];
    s += e * p[2 + t];
  }
  gv[t] = s / z;
  __syncthreads();
  float a = 0.f;
  for (int i = 0; i < HH; ++i) a += gv[i] * Wv[(size_t)i * HH + t];
  g[t] = a;
  __syncthreads();
  float b = 0.f;
  for (int i = 0; i < HH; ++i) b += g[i] * Wg[(size_t)i * HH + t];
  gterm[t] = b;
}

// ---------------- fused SpMM fp8-gather (y<3) + pool pass 1 on x8 (y==3) ----------------
__device__ __forceinline__ void acc_fp8x8(float* acc, uint2 v) {
  f32x2 a0 = __builtin_amdgcn_cvt_pk_f32_fp8(v.x, false);
  f32x2 a1 = __builtin_amdgcn_cvt_pk_f32_fp8(v.x, true);
  f32x2 a2 = __builtin_amdgcn_cvt_pk_f32_fp8(v.y, false);
  f32x2 a3 = __builtin_amdgcn_cvt_pk_f32_fp8(v.y, true);
  acc[0] += a0[0]; acc[1] += a0[1]; acc[2] += a1[0]; acc[3] += a1[1];
  acc[4] += a2[0]; acc[5] += a2[1]; acc[6] += a3[0]; acc[7] += a3[1];
}

__device__ __forceinline__ void unpack_fp8x8(float* xl, uint2 v) {
  f32x2 a0 = __builtin_amdgcn_cvt_pk_f32_fp8(v.x, false);
  f32x2 a1 = __builtin_amdgcn_cvt_pk_f32_fp8(v.x, true);
  f32x2 a2 = __builtin_amdgcn_cvt_pk_f32_fp8(v.y, false);
  f32x2 a3 = __builtin_amdgcn_cvt_pk_f32_fp8(v.y, true);
  xl[0] = a0[0]; xl[1] = a0[1]; xl[2] = a1[0]; xl[3] = a1[1];
  xl[4] = a2[0]; xl[5] = a2[1]; xl[6] = a3[0]; xl[7] = a3[1];
}

__global__ void k_spmm_pool(const int* __restrict__ offs, const int* __restrict__ csr,
                            const float* __restrict__ invc, const float* __restrict__ P,
                            const float* __restrict__ wposL,
                            const u8* __restrict__ x8,
                            u16* __restrict__ agg, const float* __restrict__ kvec,
                            float* __restrict__ part) {
  int r = blockIdx.y;
  int lane = threadIdx.x & 63;
  if (r == 3) {
    // ---- pool1: per-wave online softmax-weighted sum over x8 (fp8, 25.6 MB) ----
    if (blockIdx.x >= NPW / 4) return;
    int gw = (blockIdx.x * 256 + threadIdx.x) >> 6;
    float kl[8];
#pragma unroll
    for (int i = 0; i < 8; ++i) kl[i] = kvec[lane * 8 + i];
    float m = -1e30f, Z = 0.f;
    float acc[8] = {0, 0, 0, 0, 0, 0, 0, 0};
    for (int n = gw; n < NN; n += NPW) {
      uint2 v = *(const uint2*)(x8 + (size_t)n * HH + lane * 8);
      float xl[8], d = 0.f;
      unpack_fp8x8(xl, v);
#pragma unroll
      for (int i = 0; i < 8; ++i) d += xl[i] * kl[i];
#pragma unroll
      for (int o = 32; o > 0; o >>= 1) d += __shfl_xor(d, o);
      d *= INV_SQRT_H;
      float mn = fmaxf(m, d);
      float c = __expf(m - mn), w = __expf(d - mn);
      Z = Z * c + w;
#pragma unroll
      for (int i = 0; i < 8; ++i) acc[i] = acc[i] * c + w * xl[i];
      m = mn;
    }
    float* p = part + (size_t)gw * 514;
#pragma unroll
    for (int i = 0; i < 8; ++i) p[2 + lane * 8 + i] = acc[i];
    if (lane == 0) { p[0] = m; p[1] = Z; }
    return;
  }
  // ---- spmm: agg_r = (A_r @ x8 + P_r @ Wpos_r) * invc_r ----
  int wv = __builtin_amdgcn_readfirstlane((int)(blockIdx.x * 256 + threadIdx.x) >> 6);
  if (wv >= NN) return;
  const int* o = offs + r * (NN + 1);
  const int* cs = csr + (size_t)r * EE;
  const float* wpos = wposL + (size_t)r * 2 * HH;
  int beg = o[wv], end = o[wv + 1];
  float acc[8] = {0, 0, 0, 0, 0, 0, 0, 0};
  int k = beg;
  for (; k + 7 < end; k += 8) {        // 8 gathers in flight (8B/lane fp8)
    int s[8];
#pragma unroll
    for (int j = 0; j < 8; ++j) s[j] = cs[k + j];
    uint2 v[8];
#pragma unroll
    for (int j = 0; j < 8; ++j) v[j] = *(const uint2*)(x8 + (size_t)s[j] * HH + lane * 8);
#pragma unroll
    for (int j = 0; j < 8; ++j) acc_fp8x8(acc, v[j]);
  }
  for (; k + 3 < end; k += 4) {
    int s[4];
#pragma unroll
    for (int j = 0; j < 4; ++j) s[j] = cs[k + j];
    uint2 v[4];
#pragma unroll
    for (int j = 0; j < 4; ++j) v[j] = *(const uint2*)(x8 + (size_t)s[j] * HH + lane * 8);
#pragma unroll
    for (int j = 0; j < 4; ++j) acc_fp8x8(acc, v[j]);
  }
  for (; k < end; ++k) {
    uint2 v0 = *(const uint2*)(x8 + (size_t)cs[k] * HH + lane * 8);
    acc_fp8x8(acc, v0);
  }
  float px = P[(size_t)r * NN * 2 + 2 * wv], py = P[(size_t)r * NN * 2 + 2 * wv + 1];
  float ic = invc[(size_t)r * NN + wv];
  u16x8 out;
#pragma unroll
  for (int i = 0; i < 8; ++i) {
    float w0 = wpos[lane * 8 + i];
    float w1 = wpos[HH + lane * 8 + i];
    float v = (acc[i] + px * w0 + py * w1) * ic;
    out[i] = f2b(v);
  }
  // nt: agg streams 153 MB during the gather — keep it out of L3 so x8 stays resident
  __builtin_nontemporal_store(out, (u16x8*)(agg + ((size_t)r * MP + wv) * HH + lane * 8));
}

// ---------------- GEMM: r9-proven 128x128 tile, 4 waves, 2x __syncthreads per K-step ----------------
// FROZEN: r4/r5/r10 all proved in-kernel pipelining regresses on this shape —
// 32 KB LDS / ~5 blocks/CU inter-block overlap is the winning schedule.
// mode 0: outB = bf16(leaky(C*alpha + gvec[col])) [plain store, L3-warm for consumers];
//         if out8, fp8 copy staged through LDS -> fully coalesced 64B/thread stores.
// mode 1: outF = C + bias (bounds-checked)
__global__ __launch_bounds__(256) void k_gemm(
    const u16* __restrict__ A0, const u16* __restrict__ A1,
    const u16* __restrict__ A2, const u16* __restrict__ A3,
    const u16* __restrict__ B0, const u16* __restrict__ B1,
    const u16* __restrict__ B2, const u16* __restrict__ B3,
    int nkt, int mode, float alpha, const float* __restrict__ gvec,
    u16* __restrict__ outB, u8* __restrict__ out8, float* __restrict__ outF,
    const float* __restrict__ bias, int M, int Nout, int G, int gx)
{
  __shared__ u16 lsA[128 * 64];
  __shared__ u16 lsB[128 * 64];
  const int tid = threadIdx.x;
  const int wave = tid >> 6, lane = tid & 63;
  const int wm = (wave >> 1) * 64, wn = (wave & 1) * 64;

  // bijective XCD swizzle (m204), col-fastest tile order
  const int gid = blockIdx.x;
  const int q = G >> 3, rr = G & 7;
  const int xk = gid & 7, idx = gid >> 3;
  const int tl = xk * q + (xk < rr ? xk : rr) + idx;
  const int rowM0 = (tl / gx) * 128, colN0 = (tl % gx) * 128;

  f32x4 acc[4][4];
#pragma unroll
  for (int i = 0; i < 4; ++i)
#pragma unroll
    for (int j = 0; j < 4; ++j) acc[i][j] = (f32x4){0.f, 0.f, 0.f, 0.f};

  const int rowT = wave * 8 + (lane >> 3);
  const int c8 = lane & 7;
  // hoisted kt-invariant LDS read offsets (u16 units)
  int aoff[2][4], boff[2][4];
#pragma unroll
  for (int K0 = 0; K0 < 2; ++K0)
#pragma unroll
    for (int f = 0; f < 4; ++f) {
      const int cb = K0 * 4 + (lane >> 4);
      const int mm = wm + f * 16 + (lane & 15);
      const int nn = wn + f * 16 + (lane & 15);
      aoff[K0][f] = mm * 64 + ((cb ^ (mm & 7)) << 3);
      boff[K0][f] = nn * 64 + ((cb ^ (nn & 7)) << 3);
    }

  const int nkb = nkt >> 3;
  for (int kb = 0; kb < nkb; ++kb) {
    const u16* As = kb == 0 ? A0 : (kb == 1 ? A1 : (kb == 2 ? A2 : A3));
    const u16* Bs = kb == 0 ? B0 : (kb == 1 ? B1 : (kb == 2 ? B2 : B3));
    for (int k8 = 0; k8 < 8; ++k8) {
      const int koff = k8 * 64;
#pragma unroll
      for (int i = 0; i < 4; ++i) {
        const int r = i * 32 + rowT;
        const int scol = (c8 ^ (r & 7)) * 8;   // inverse-swizzled global source
        async16(As + (size_t)(rowM0 + r) * HH + koff + scol, &lsA[i * 2048 + wave * 512]);
        async16(Bs + (size_t)(colN0 + r) * HH + koff + scol, &lsB[i * 2048 + wave * 512]);
      }
      __syncthreads();
#pragma unroll
      for (int K0 = 0; K0 < 2; ++K0) {
        s16x8 af[4], bfr[4];
#pragma unroll
        for (int f = 0; f < 4; ++f) {
          af[f] = *(const s16x8*)&lsA[aoff[K0][f]];
          bfr[f] = *(const s16x8*)&lsB[boff[K0][f]];
        }
#pragma unroll
        for (int fm = 0; fm < 4; ++fm)
#pragma unroll
          for (int fn = 0; fn < 4; ++fn)
            acc[fm][fn] = __builtin_amdgcn_mfma_f32_16x16x32_bf16(af[fm], bfr[fn], acc[fm][fn], 0, 0, 0);
      }
      __syncthreads();
    }
  }

  u8* l8 = (u8*)lsA;   // safe to reuse after the final K-loop barrier
#pragma unroll
  for (int fm = 0; fm < 4; ++fm) {
#pragma unroll
    for (int fn = 0; fn < 4; ++fn) {
#pragma unroll
      for (int r = 0; r < 4; ++r) {
        const int rit = wm + fm * 16 + ((lane >> 4) << 2) + r;   // row in tile (m89 layout)
        const int cit = wn + fn * 16 + (lane & 15);              // col in tile
        const int row = rowM0 + rit, col = colN0 + cit;
        float v = acc[fm][fn][r];
        if (mode == 0) {
          v = leakyf(v * alpha + (gvec ? gvec[col] : 0.f));
          outB[(size_t)row * HH + col] = f2b(v);
          if (out8) {
            int pk = __builtin_amdgcn_cvt_pk_fp8_f32(v, v, 0, false);
            l8[rit * 128 + cit] = (u8)pk;
          }
        } else {
          if (row < M && col < Nout)
            outF[(size_t)row * Nout + col] = v + (bias ? bias[col] : 0.f);
        }
      }
    }
  }
  if (mode == 0 && out8) {
    __syncthreads();
    const int rit = tid >> 1, hoff = (tid & 1) * 64;
    const uint4* src = (const uint4*)(l8 + rit * 128 + hoff);
    uint4 v0 = src[0], v1 = src[1], v2 = src[2], v3 = src[3];
    uint4* dst = (uint4*)(out8 + (size_t)(rowM0 + rit) * HH + colN0 + hoff);
    dst[0] = v0; dst[1] = v1; dst[2] = v2; dst[3] = v3;
  }
}

// ---------------- host ----------------
extern "C" void kernel_launch(void* const* d_in, const int* in_sizes, int n_in,
                              void* d_out, int out_size, void* d_ws, size_t ws_size,
                              hipStream_t stream) {
  (void)in_sizes; (void)n_in; (void)out_size;
  const float* x_window = (const float*)d_in[0];
  const float* x_pos    = (const float*)d_in[1];
  const int*   e0 = (const int*)d_in[2];
  const int*   e1 = (const int*)d_in[3];
  const int*   e2 = (const int*)d_in[4];
  const float* W_pre  = (const float*)d_in[5];
  const float* W_post = (const float*)d_in[6];
  const float* Wl   = (const float*)d_in[7];
  const float* Wr   = (const float*)d_in[8];
  const float* Wpos = (const float*)d_in[9];
  const float* Wg   = (const float*)d_in[10];
  const float* seed = (const float*)d_in[11];
  const float* Wk   = (const float*)d_in[12];
  const float* Wv   = (const float*)d_in[13];
  const float* W_out= (const float*)d_in[14];
  const float* b_out= (const float*)d_in[15];
  float* out = (float*)d_out;

  char* base = (char*)d_ws;
  size_t off = 0;
  auto alloc = [&](size_t bytes) -> char* {
    char* p = base + off;
    off += (bytes + 255) & ~(size_t)255;
    return p;
  };
  u16* x_a   = (u16*)alloc((size_t)MP * HH * 2);
  u16* x_b   = (u16*)alloc((size_t)MP * HH * 2);
  u16* agg0  = (u16*)alloc((size_t)MP * HH * 2);
  u16* agg1  = (u16*)alloc((size_t)MP * HH * 2);
  u16* agg2  = (u16*)alloc((size_t)MP * HH * 2);
  u8*  x8    = (u8*)alloc((size_t)MP * HH);
  u16* wlT   = (u16*)alloc((size_t)12 * HH2 * 2);
  u16* wrsT  = (u16*)alloc((size_t)4 * HH2 * 2);
  u16* wpreT = (u16*)alloc((size_t)HH2 * 2);
  u16* wpostT= (u16*)alloc((size_t)HH2 * 2);
  u16* woutT = (u16*)alloc((size_t)256 * HH * 2);
  int* offs  = (int*)alloc((size_t)3 * (NN + 1) * 4);
  int* curs  = (int*)alloc((size_t)3 * NN * 4);    // dead after CSR build -> part overlay
  int* cnt   = (int*)alloc((size_t)3 * NN * 4);    // dead after scan
  int* csr   = (int*)alloc((size_t)3 * EE * 4);
  float* invc = (float*)alloc((size_t)3 * NN * 4);
  float* P    = (float*)alloc((size_t)3 * NN * 2 * 4);
  float* kvec  = (float*)alloc((size_t)LL * HH * 4);
  float* gterm = (float*)alloc(HH * 4);
  int* bsum  = (int*)alloc((size_t)3 * NBLK * 4);
  float* part  = (float*)curs;   // NPW*514*4 = 1.05 MB fits in curs+cnt (1.2 MB)
  if (off > ws_size) return;

  hipMemsetAsync(cnt, 0, (size_t)3 * NN * 4, stream);

  k_hist<<<dim3((EE + 255) / 256, 3), 256, 0, stream>>>(e0, e1, e2, cnt);
  k_scan1<<<dim3(NBLK, 3), 1024, 0, stream>>>(cnt, offs, invc, bsum);
  k_scan2<<<1, 256, 0, stream>>>(bsum);
  k_scan3<<<dim3(NBLK, 3), 1024, 0, stream>>>(bsum, offs, curs);
  k_fill<<<dim3((EE + 255) / 256, 3), 256, 0, stream>>>(e0, e1, e2, curs, csr);
  k_pvec<<<dim3((NN + 255) / 256, 3), 256, 0, stream>>>(offs, csr, (const float2*)x_pos, P);

  k_transT14<<<dim3(16, 16, 14), dim3(32, 8), 0, stream>>>(Wl, W_pre, W_post,
                                                           wlT, wpreT, wpostT);
  k_sum3T<<<dim3(16, 16, 4), dim3(32, 8), 0, stream>>>(Wr, wrsT);
  k_transpose_pad<<<(HH * 256) / 256, 256, 0, stream>>>(W_out, woutT, HH, OUTC, 256);
  k_kvec<<<LL, 512, 0, stream>>>(Wk, seed, kvec);

  const int padBlk = ((MP - NN) * HH * 5 + 255) / 256;
  k_cvt_zero<<<CVT_BLK + padBlk, 256, 0, stream>>>(x_window, x_b, x_a, x_b, agg0, agg1, agg2);

  const u16* nul = nullptr;
  const int G4 = 4 * (MP / 128), G2 = 2 * (MP / 128);
  // pretransform: t = leaky(xw @ W_pre) -> agg0 ; x0 = leaky(t @ W_post) -> x_a (+fp8)
  k_gemm<<<G4, 256, 0, stream>>>(x_b, nul, nul, nul, wpreT, nul, nul, nul,
                                 8, 0, 1.f, nullptr, agg0, nullptr, nullptr, nullptr, NN, HH, G4, 4);
  k_gemm<<<G4, 256, 0, stream>>>(agg0, nul, nul, nul, wpostT, nul, nul, nul,
                                 8, 0, 1.f, nullptr, x_a, x8, nullptr, nullptr, NN, HH, G4, 4);

  u16* cur = x_a; u16* nxt = x_b;
  for (int l = 0; l < LL; ++l) {
    k_spmm_pool<<<dim3(NN / 4, 4), 256, 0, stream>>>(offs, csr, invc, P,
                                                     Wpos + (size_t)l * 3 * 2 * HH, x8, agg0,
                                                     kvec + (size_t)l * HH, part);
    k_pool2g<<<1, 512, 0, stream>>>(part, Wv + (size_t)l * HH2, Wg + (size_t)l * HH2, gterm);
    k_gemm<<<G4, 256, 0, stream>>>(
        agg0, agg1, agg2, cur,
        wlT + (size_t)(l * 3 + 0) * HH2, wlT + (size_t)(l * 3 + 1) * HH2,
        wlT + (size_t)(l * 3 + 2) * HH2, wrsT + (size_t)l * HH2,
        32, 0, (1.f / 3.f), gterm, nxt, (l < LL - 1) ? x8 : nullptr, nullptr, nullptr, NN, HH, G4, 4);
    u16* t = cur; cur = nxt; nxt = t;
  }
  // final projection: out = x @ W_out + b_out
  k_gemm<<<G2, 256, 0, stream>>>(cur, nul, nul, nul, woutT, nul, nul, nul,
                                 8, 1, 1.f, nullptr, nullptr, nullptr, out, b_out, NN, OUTC, G2, 2);
}